// Round 1
// baseline (409.824 us; speedup 1.0000x reference)
//
#include <hip/hip_runtime.h>

// ImageBuffer: sliding-window gather.
//   combined = concat(buffer[16 frames], inputs[128 frames])   frame = H*W*C floats
//   out[b][k] = combined[b + 1 + k],  b in [0,128), k in [0,16)
// Pure bandwidth problem: 402.7 MB write, ~28 MB unique read.

constexpr int BATCH     = 128;
constexpr int KBUF      = 16;
constexpr int FRAME_F32 = 128 * 128 * 3;      // 49152 floats per frame
constexpr int FRAME_F4  = FRAME_F32 / 4;      // 12288 float4 per frame
constexpr int BLOCK     = 256;
constexpr int CHUNKS    = FRAME_F4 / BLOCK;   // 48 blocks per output frame

__global__ __launch_bounds__(BLOCK)
void ImageBuffer_86784109183359_kernel(const float4* __restrict__ inputs,
                                       const float4* __restrict__ buffer,
                                       float4* __restrict__ out) {
    const int bid   = blockIdx.x;
    const int frame = bid / CHUNKS;           // output frame index: b*16 + k
    const int chunk = bid % CHUNKS;
    const int off   = chunk * BLOCK + threadIdx.x;   // float4 offset within frame

    const int b = frame >> 4;                 // batch index
    const int k = frame & 15;                 // window position
    const int j = b + 1 + k;                  // source frame in `combined`

    // Branch is uniform per block (frame is block-constant) — no divergence.
    const float4* __restrict__ src =
        (j < KBUF) ? (buffer + (size_t)j * FRAME_F4)
                   : (inputs + (size_t)(j - KBUF) * FRAME_F4);

    out[(size_t)frame * FRAME_F4 + off] = src[off];
}

extern "C" void kernel_launch(void* const* d_in, const int* in_sizes, int n_in,
                              void* d_out, int out_size, void* d_ws, size_t ws_size,
                              hipStream_t stream) {
    const float4* inputs = (const float4*)d_in[0];  // [128,128,128,3] fp32
    const float4* buffer = (const float4*)d_in[1];  // [16,128,128,3] fp32
    float4* out = (float4*)d_out;                   // [128,16,128,128,3] fp32

    const int n_frames = BATCH * KBUF;              // 2048 output frames
    const int grid = n_frames * CHUNKS;             // 98304 blocks

    ImageBuffer_86784109183359_kernel<<<grid, BLOCK, 0, stream>>>(inputs, buffer, out);
}